// Round 1
// baseline (69.364 us; speedup 1.0000x reference)
//
#include <hip/hip_runtime.h>
#include <math.h>

// Problem constants (match reference file)
constexpr int B = 128;    // batch
constexpr int I = 2048;   // IN_DIM  (mask cols / variable nodes)
constexpr int O = 1024;   // OUT_DIM (mask rows / check nodes)
constexpr int OT  = 4;    // mask rows handled per block (grid = O/OT = 256 blocks)
constexpr int CAP = 64;   // max stored nonzeros per row (E[nnz]=8, P(nnz>64) ~ 1e-40)

// ---------------------------------------------------------------------------
// Kernel 1: transpose x [B][I] -> xT [I][B] so the per-index gather in the
// main kernel is coalesced across the batch dimension.
// ---------------------------------------------------------------------------
__global__ __launch_bounds__(256) void transpose_x(const float* __restrict__ x,
                                                   float* __restrict__ xT) {
    __shared__ float tile[32][33];  // +1 pad: avoid LDS bank conflicts
    const int bx = blockIdx.x * 32;  // column tile base (I dim)
    const int by = blockIdx.y * 32;  // row tile base    (B dim)
    const int tx = threadIdx.x;      // 0..31
    const int ty = threadIdx.y;      // 0..7

#pragma unroll
    for (int j = 0; j < 32; j += 8) {
        tile[ty + j][tx] = x[(by + ty + j) * I + (bx + tx)];  // coalesced read
    }
    __syncthreads();
#pragma unroll
    for (int j = 0; j < 32; j += 8) {
        xT[(bx + ty + j) * B + (by + tx)] = tile[tx][ty + j]; // coalesced write
    }
}

// ---------------------------------------------------------------------------
// Kernel 2: per block, scan OT mask rows -> compact nonzero column indices in
// LDS, then each thread computes 2 outputs: product of x[b, idx] over the
// row's indices, clamp, 2*atanh via log((1+p)/(1-p)).
// Block = 256 threads: b = t & 127, oh = t >> 7 selects which row pair.
// ---------------------------------------------------------------------------
__global__ __launch_bounds__(256) void bp_checknode(const float* __restrict__ mask,
                                                    const float* __restrict__ xT,
                                                    float* __restrict__ out) {
    __shared__ int s_idx[OT][CAP];
    __shared__ int s_nnz[OT];

    const int t = threadIdx.x;
    const int obase = blockIdx.x * OT;

    if (t < OT) s_nnz[t] = 0;
    __syncthreads();

    // ---- Phase 1: scan OT contiguous mask rows (OT*I floats) with float4 ----
    const float4* m4 = reinterpret_cast<const float4*>(mask + (size_t)obase * I);
    constexpr int ITERS = OT * I / 4 / 256;  // = 8
#pragma unroll
    for (int it = 0; it < ITERS; ++it) {
        const int v4i = it * 256 + t;       // float4 index within the block's region
        const float4 v = m4[v4i];
        const int e = v4i * 4;              // element offset within region
        const int r = e >> 11;              // row within block (I = 2048)
        const int c = e & (I - 1);          // column
        if (v.x != 0.0f) { int p = atomicAdd(&s_nnz[r], 1); if (p < CAP) s_idx[r][p] = c + 0; }
        if (v.y != 0.0f) { int p = atomicAdd(&s_nnz[r], 1); if (p < CAP) s_idx[r][p] = c + 1; }
        if (v.z != 0.0f) { int p = atomicAdd(&s_nnz[r], 1); if (p < CAP) s_idx[r][p] = c + 2; }
        if (v.w != 0.0f) { int p = atomicAdd(&s_nnz[r], 1); if (p < CAP) s_idx[r][p] = c + 3; }
    }
    __syncthreads();

    // ---- Phase 2: products. thread -> (b, row pair) ----
    const int b  = t & (B - 1);  // 0..127
    const int oh = t >> 7;       // 0..1
    const float hi = 1.0f - 1e-7f;  // rounds to 1 - 2^-23, same as numpy's f32 clip bound

    float res[2];
#pragma unroll
    for (int rr = 0; rr < 2; ++rr) {
        const int r = oh * 2 + rr;
        const int n = min(s_nnz[r], CAP);
        float p = 1.0f;
        for (int k = 0; k < n; ++k) {
            p *= xT[s_idx[r][k] * B + b];   // coalesced: consecutive b = consecutive addr
        }
        p = fminf(fmaxf(p, -hi), hi);
        res[rr] = logf((1.0f + p) / (1.0f - p));
    }

    // contiguous 8B store: out[b][obase + oh*2 .. +1]
    *reinterpret_cast<float2*>(out + (size_t)b * O + obase + oh * 2) =
        make_float2(res[0], res[1]);
}

// ---------------------------------------------------------------------------
extern "C" void kernel_launch(void* const* d_in, const int* in_sizes, int n_in,
                              void* d_out, int out_size, void* d_ws, size_t ws_size,
                              hipStream_t stream) {
    const float* x    = (const float*)d_in[0];   // [B][I]  = 128*2048
    const float* mask = (const float*)d_in[1];   // [O][I]  = 1024*2048
    float* out = (float*)d_out;                  // [B][O]  = 128*1024
    float* xT  = (float*)d_ws;                   // [I][B]  = 1 MB scratch

    dim3 tb(32, 8);
    dim3 tg(I / 32, B / 32);                     // (64, 4)
    transpose_x<<<tg, tb, 0, stream>>>(x, xT);

    bp_checknode<<<O / OT, 256, 0, stream>>>(mask, xT, out);
}

// Round 3
// 68.518 us; speedup vs baseline: 1.0123x; 1.0123x over previous
//
#include <hip/hip_runtime.h>
#include <math.h>

// Problem constants (match reference file)
constexpr int B = 128;    // batch
constexpr int I = 2048;   // IN_DIM  (mask cols)
constexpr int O = 1024;   // OUT_DIM (mask rows)
constexpr int OT  = 2;    // mask rows per block -> grid = 512 blocks (2/CU)
constexpr int CAP = 64;   // max stored nonzeros/row (E[nnz]=8, P(nnz>64)~1e-40)
constexpr int PRE = 16;   // branchless register-prefetch width (P(nnz>16)~0.3%)

// Single fused kernel:
//  Phase 1: scan OT mask rows (float4, coalesced), compact nonzero column
//           indices into LDS via shared-counter atomics (product order is
//           commutative; fp reorder noise << threshold).
//  Phase 2: each thread owns one (batch b, row r): branchless prefetch of 16
//           gathers from x (L2-resident, 1 MB) -> product tree -> clamp ->
//           2*atanh via log((1+p)/(1-p)). Rare nnz>16 tail via loop.
//  Store:   LDS exchange so each batch writes one contiguous float2.
__global__ __launch_bounds__(256) void bp_fused(const float* __restrict__ x,
                                                const float* __restrict__ mask,
                                                float* __restrict__ out) {
    __shared__ int   s_idx[OT][CAP];
    __shared__ int   s_nnz[OT];
    __shared__ float s_res[OT][B];

    const int t = threadIdx.x;
    const int obase = blockIdx.x * OT;

    if (t < OT) s_nnz[t] = 0;
    if (t < OT * CAP) ((int*)s_idx)[t] = 0;   // make unwritten slots a SAFE index
    __syncthreads();

    // ---- Phase 1: scan OT contiguous mask rows (OT*I floats) with float4 ----
    const float4* m4 = reinterpret_cast<const float4*>(mask + (size_t)obase * I);
    constexpr int ITERS = OT * I / 4 / 256;   // = 4
#pragma unroll
    for (int it = 0; it < ITERS; ++it) {
        const int v4i = it * 256 + t;
        const float4 v = m4[v4i];
        const int e = v4i * 4;
        const int r = e >> 11;               // row within block (I = 2048)
        const int c = e & (I - 1);           // column
        if (v.x != 0.0f) { int p = atomicAdd(&s_nnz[r], 1); if (p < CAP) s_idx[r][p] = c; }
        if (v.y != 0.0f) { int p = atomicAdd(&s_nnz[r], 1); if (p < CAP) s_idx[r][p] = c + 1; }
        if (v.z != 0.0f) { int p = atomicAdd(&s_nnz[r], 1); if (p < CAP) s_idx[r][p] = c + 2; }
        if (v.w != 0.0f) { int p = atomicAdd(&s_nnz[r], 1); if (p < CAP) s_idx[r][p] = c + 3; }
    }
    __syncthreads();

    // ---- Phase 2: one (b, r) per thread ----
    const int b = t & (B - 1);               // 0..127
    const int r = t >> 7;                    // 0..1  (uniform per wave)
    const int n = min(s_nnz[r], CAP);
    const float* xb = x + (size_t)b * I;

    // Branchless prefetch: 16 independent gathers issued back-to-back
    // (idx uniform per wave, lanes = consecutive b -> 256B coalesced loads).
    float v[PRE];
#pragma unroll
    for (int k = 0; k < PRE; ++k) {
        const float xv = xb[s_idx[r][k]];    // always in-bounds (idx 0 if unwritten)
        v[k] = (k < n) ? xv : 1.0f;
    }
    // depth-4 product tree
#pragma unroll
    for (int s = PRE / 2; s >= 1; s >>= 1)
#pragma unroll
        for (int k = 0; k < s; ++k) v[k] *= v[k + s];
    float p = v[0];
    for (int k = PRE; k < n; ++k) p *= xb[s_idx[r][k]];   // rare tail

    const float hi = 1.0f - 1e-7f;           // rounds to 1 - 2^-23, same as f32 clip
    p = fminf(fmaxf(p, -hi), hi);
    s_res[r][b] = logf((1.0f + p) / (1.0f - p));
    __syncthreads();

    // ---- Store: one contiguous float2 per batch ----
    if (t < B) {
        *reinterpret_cast<float2*>(out + (size_t)t * O + obase) =
            make_float2(s_res[0][t], s_res[1][t]);
    }
}

// ---------------------------------------------------------------------------
extern "C" void kernel_launch(void* const* d_in, const int* in_sizes, int n_in,
                              void* d_out, int out_size, void* d_ws, size_t ws_size,
                              hipStream_t stream) {
    const float* x    = (const float*)d_in[0];   // [B][I]  = 128*2048
    const float* mask = (const float*)d_in[1];   // [O][I]  = 1024*2048
    float* out = (float*)d_out;                  // [B][O]  = 128*1024

    bp_fused<<<O / OT, 256, 0, stream>>>(x, mask, out);
}